// Round 9
// baseline (283.315 us; speedup 1.0000x reference)
//
#include <hip/hip_runtime.h>
#include <cstddef>

// Problem constants
constexpr int CB  = 4;
constexpr int CC  = 192;
constexpr int CH  = 64;
constexpr int CW  = 64;
constexpr int CL  = CH * CW;        // 4096
constexpr int DIN = 384;
constexpr int NST = 16;
constexpr int DTR = 12;

constexpr int NCHUNK = 64;          // chunks per sequence (= image rows)
constexpr int NELEM  = CB * DIN * NST; // 24576 independent (b,d,n) recurrences

// Workspace layout (in floats)
constexpr int WS_PART  = 0;                          // 512
constexpr int WS_STAT  = 512;                        // 8
constexpr int WS_BFIN  = 1024;                       // 147456 f16 = 73728 fl
constexpr int WS_W2F   = WS_BFIN + 73728;            // 73728 f16 = 36864 fl
constexpr int WS_BFXF  = WS_W2F + 36864;             // 172032 f16 = 86016 fl
constexpr int WS_LWT   = WS_BFXF + 86016;            // 3456 fl
constexpr int WS_BIG   = WS_LWT + 3456;              // = 201088
constexpr size_t NBL   = (size_t)CB * CL;            // 16384
constexpr size_t BIGSZ = NBL * DIN;                  // 6291456 floats

using half8 = __attribute__((ext_vector_type(8))) _Float16;
using half4 = __attribute__((ext_vector_type(4))) _Float16;
using f32x4 = __attribute__((ext_vector_type(4))) float;

__device__ __forceinline__ float sigm(float v) { return 1.f / (1.f + __expf(-v)); }
__device__ __forceinline__ float silu_f(float v) { return v * sigm(v); }
__device__ __forceinline__ float softplus_f(float v) { return v > 20.f ? v : log1pf(__expf(v)); }
template <int PAT>
__device__ __forceinline__ float quadswz(float v) {
  return __int_as_float(__builtin_amdgcn_ds_swizzle(__float_as_int(v), PAT));
}

// A-fragment index: value = A[m][k]
__device__ __forceinline__ size_t afrag_idx(int m, int k, int KS) {
  int m16 = m >> 4, r16 = m & 15;
  int ks = k >> 5, kg = (k & 31) >> 3, j = k & 7;
  return (((size_t)(m16 * KS + ks)) << 9) + (size_t)(((kg << 4) + r16) << 3) + j;
}
// B-fragment index: value = W[col][k]
__device__ __forceinline__ size_t bfrag_idx(int col, int k, int KS) {
  int nt = col >> 6, colq = (col >> 4) & 3, r16 = col & 15;
  int ks = k >> 5, kg = (k & 31) >> 3, j = k & 7;
  return (((size_t)((nt * KS + ks) * 4 + colq)) << 9) + (size_t)(((kg << 4) + r16) << 3) + j;
}

// ---------------------------------------------------------------------------
// Prep: (blocks 0..17) compose W2 = proj_out_w @ out_proj_w into fp16 B-frags;
// (blocks 18..273) GroupNorm partial sums; (rest) weight packing.
// ---------------------------------------------------------------------------
__device__ __forceinline__ void pack_frag(_Float16* dst, int idx, int KS,
                                          const float* __restrict__ W, int KDIM) {
  int j = idx & 7, lane = (idx >> 3) & 63, colq = (idx >> 9) & 3, rest = idx >> 11;
  int ks = rest % KS, nt = rest / KS;
  int col = nt * 64 + colq * 16 + (lane & 15);
  int k = ks * 32 + ((lane >> 4) << 3) + j;
  dst[idx] = (_Float16)W[(size_t)col * KDIM + k];
}

__device__ __forceinline__ void pack_xf(_Float16* dst, int idx,
                                        const float* __restrict__ xw,
                                        const float* __restrict__ dtw) {
  int j = idx & 7, lane = (idx >> 3) & 63, colq = (idx >> 9) & 3, rest = idx >> 11;
  int ks = rest % 12, nt = rest / 12;
  int col = nt * 64 + colq * 16 + (lane & 15);
  int k = ks * 32 + ((lane >> 4) << 3) + j;
  float v = 0.f;
  if (col < 384) {
#pragma unroll
    for (int r = 0; r < 12; r++)
      v += xw[r * 384 + k] * dtw[col * 12 + r];
  } else if (col < 416) {
    v = xw[(col - 384 + 12) * 384 + k];
  }
  dst[idx] = (_Float16)v;
}

__global__ __launch_bounds__(256) void prep_kernel(
    const float* __restrict__ x, const float* __restrict__ in_proj_w,
    const float* __restrict__ x_proj_w, const float* __restrict__ dt_proj_w,
    const float* __restrict__ out_proj_w, const float* __restrict__ proj_out_w,
    const float* __restrict__ le_w, float* __restrict__ ws) {
  __shared__ float Ps[16][65];
  __shared__ float Os[16][65];
  __shared__ float ls[4], ls2[4];
  int bid = blockIdx.x;
  int tid = threadIdx.x;
  if (bid < 18) {
    // W2[col][k] = sum_c proj_out_w[col*192+c] * out_proj_w[c*384+k]
    int ct = bid / 6, kt = bid % 6;
    int co0 = ct * 64, k0 = kt * 64;
    int tx = tid & 15, ty = tid >> 4;
    float acc[4][4] = {};
    for (int c0 = 0; c0 < 192; c0 += 16) {
      for (int i2 = tid; i2 < 1024; i2 += 256) {
        int cc = i2 >> 6, e = i2 & 63;
        Ps[cc][e] = proj_out_w[(size_t)(co0 + e) * 192 + c0 + cc];
        Os[cc][e] = out_proj_w[(size_t)(c0 + cc) * 384 + k0 + e];
      }
      __syncthreads();
#pragma unroll
      for (int kk = 0; kk < 16; kk++) {
        float a[4], b[4];
#pragma unroll
        for (int i = 0; i < 4; i++) a[i] = Ps[kk][tx + 16 * i];
#pragma unroll
        for (int j = 0; j < 4; j++) b[j] = Os[kk][ty + 16 * j];
#pragma unroll
        for (int i = 0; i < 4; i++)
#pragma unroll
          for (int j = 0; j < 4; j++) acc[i][j] = fmaf(a[i], b[j], acc[i][j]);
      }
      __syncthreads();
    }
    _Float16* w2f = (_Float16*)(ws + WS_W2F);
#pragma unroll
    for (int i = 0; i < 4; i++)
#pragma unroll
      for (int j = 0; j < 4; j++)
        w2f[bfrag_idx(co0 + tx + 16 * i, k0 + ty + 16 * j, 12)] = (_Float16)acc[i][j];
    return;
  }
  if (bid < 18 + 256) {
    int gid = bid - 18;
    int b = gid >> 6, chunk = gid & 63;
    const float* px = x + (size_t)b * CC * CL + (size_t)chunk * 12288;
    float s = 0.f, s2 = 0.f;
    for (int i = tid; i < 12288 / 4; i += 256) {
      float4 v = ((const float4*)px)[i];
      s  += v.x + v.y + v.z + v.w;
      s2 += v.x * v.x + v.y * v.y + v.z * v.z + v.w * v.w;
    }
    for (int off = 32; off; off >>= 1) { s += __shfl_down(s, off); s2 += __shfl_down(s2, off); }
    int wid = tid >> 6, lane = tid & 63;
    if (lane == 0) { ls[wid] = s; ls2[wid] = s2; }
    __syncthreads();
    if (tid == 0) {
      float t = 0.f, t2 = 0.f;
      for (int i = 0; i < 4; i++) { t += ls[i]; t2 += ls2[i]; }
      ws[WS_PART + gid * 2] = t;
      ws[WS_PART + gid * 2 + 1] = t2;
    }
    return;
  }
  int idx = (bid - 274) * 256 + tid;
  if (idx < 147456) {                 // in_proj: 768 cols x 192 k, KS=6
    pack_frag((_Float16*)(ws + WS_BFIN), idx, 6, in_proj_w, 192);
    return;
  }
  idx -= 147456;
  if (idx < 172032) {                 // fused x_proj/dt_proj: 448 cols, KS=12
    pack_xf((_Float16*)(ws + WS_BFXF), idx, x_proj_w, dt_proj_w);
    return;
  }
  idx -= 172032;
  if (idx < 3456) {                   // lwT[t9][d] = le_w[d*9 + t9]
    int t9 = idx / 384, d = idx % 384;
    ws[WS_LWT + idx] = le_w[d * 9 + t9];
  }
}

__global__ __launch_bounds__(256) void gn_final(const float* __restrict__ part,
                                                float* __restrict__ stat) {
  int b = threadIdx.x >> 6;   // wave id == batch
  int i = threadIdx.x & 63;
  float s = part[(b * 64 + i) * 2];
  float s2 = part[(b * 64 + i) * 2 + 1];
  for (int off = 32; off; off >>= 1) { s += __shfl_down(s, off); s2 += __shfl_down(s2, off); }
  if (i == 0) {
    float n = (float)(CC * CL);
    float mu = s / n;
    float var = s2 / n - mu * mu;
    stat[b * 2] = mu;
    stat[b * 2 + 1] = rsqrtf(var + 1e-5f);
  }
}

// ---------------------------------------------------------------------------
// in_proj GEMM via fp16 MFMA with fused GroupNorm. Epilogue re-stages acc
// through LDS (reusing Ah) and writes u (snake) / z (raster) as float4 rows.
// ---------------------------------------------------------------------------
__global__ __launch_bounds__(256) void gemm_inproj_mfma(
    const float* __restrict__ x, const _Float16* __restrict__ Bf,
    const float* __restrict__ stat, const float* __restrict__ gamma,
    const float* __restrict__ beta, float* __restrict__ u, float* __restrict__ z) {
  int mt = blockIdx.x & 255, nt = blockIdx.x >> 8;   // nt 0..11
  int m0 = mt * 64;
  int b = m0 >> 12, l0 = m0 & 4095;
  float mu = stat[b * 2], rs = stat[b * 2 + 1];
  __shared__ __align__(16) _Float16 Ah[64][200];
  int tid = threadIdx.x;
  int row = tid & 63, cq = tid >> 6;
#pragma unroll
  for (int i = 0; i < 12; i++) {
    int c0 = cq * 4 + i * 16;
    half4 h;
#pragma unroll
    for (int cc = 0; cc < 4; cc++) {
      int c = c0 + cc;
      float g = gamma[c] * rs;
      float bt = beta[c] - mu * g;
      float xv = x[((size_t)(b * 192 + c) << 12) + l0 + row];
      h[cc] = (_Float16)(xv * g + bt);
    }
    *(half4*)&Ah[row][c0] = h;
  }
  __syncthreads();
  int w = tid >> 6, lane = tid & 63;
  int wm = (w >> 1) * 32, wcol = w & 1;
  int r16 = lane & 15, kg = lane >> 4;
  f32x4 acc[2][2] = {};
#pragma unroll
  for (int ks = 0; ks < 6; ks++) {
    half8 a0 = *(const half8*)&Ah[wm + r16][ks * 32 + kg * 8];
    half8 a1 = *(const half8*)&Ah[wm + 16 + r16][ks * 32 + kg * 8];
    half8 b0 = *(const half8*)&Bf[(((size_t)(nt * 6 + ks) * 4 + wcol * 2 + 0) << 9) + lane * 8];
    half8 b1 = *(const half8*)&Bf[(((size_t)(nt * 6 + ks) * 4 + wcol * 2 + 1) << 9) + lane * 8];
    acc[0][0] = __builtin_amdgcn_mfma_f32_16x16x32_f16(a0, b0, acc[0][0], 0, 0, 0);
    acc[0][1] = __builtin_amdgcn_mfma_f32_16x16x32_f16(a0, b1, acc[0][1], 0, 0, 0);
    acc[1][0] = __builtin_amdgcn_mfma_f32_16x16x32_f16(a1, b0, acc[1][0], 0, 0, 0);
    acc[1][1] = __builtin_amdgcn_mfma_f32_16x16x32_f16(a1, b1, acc[1][1], 0, 0, 0);
  }
  // Re-stage through LDS (Ah dead) -> float4 stores.
  float* CsF = (float*)&Ah[0][0];      // [64][68]
  __syncthreads();
#pragma unroll
  for (int mi = 0; mi < 2; mi++)
#pragma unroll
    for (int ni = 0; ni < 2; ni++)
#pragma unroll
      for (int r = 0; r < 4; r++)
        CsF[(wm + mi * 16 + kg * 4 + r) * 68 + wcol * 32 + ni * 16 + r16] = acc[mi][ni][r];
  __syncthreads();
  int hrow = l0 >> 6;
  bool odd = hrow & 1;
  int srow = tid >> 2, fq = tid & 3;
  if (nt < 6) {
    int ls = odd ? (hrow << 6) + 63 - srow : l0 + srow;
    float* dst = &u[((size_t)(b << 12) + ls) * DIN + nt * 64 + fq * 16];
#pragma unroll
    for (int c = 0; c < 4; c++)
      *(float4*)&dst[c * 4] = *(float4*)&CsF[srow * 68 + fq * 16 + c * 4];
  } else {
    float* dst = &z[((size_t)(b << 12) + l0 + srow) * DIN + (nt - 6) * 64 + fq * 16];
#pragma unroll
    for (int c = 0; c < 4; c++)
      *(float4*)&dst[c * 4] = *(float4*)&CsF[srow * 68 + fq * 16 + c * 4];
  }
}

// ---------------------------------------------------------------------------
// Fused x_proj + dt_proj, LDS-free A (uc_h frags). nt<6: float4 softplus
// delta stores via LDS; nt==6: B/C scalar stores.
// ---------------------------------------------------------------------------
__global__ __launch_bounds__(256) void xfull_direct(
    const _Float16* __restrict__ Af, const _Float16* __restrict__ Bf,
    const float* __restrict__ dt_bias, float* __restrict__ delta,
    float* __restrict__ Bmb, float* __restrict__ Cmb) {
  int mt = blockIdx.x & 255, nt = blockIdx.x >> 8;   // nt 0..6
  int m0 = mt * 64;
  __shared__ float Cs[64][68];
  int tid = threadIdx.x;
  int w = tid >> 6, lane = tid & 63;
  int wm = (w >> 1) * 32, wcol = w & 1;
  int r16 = lane & 15, kg = lane >> 4;
  int m16a = (m0 + wm) >> 4;
  f32x4 acc[2][2] = {};
#pragma unroll
  for (int ks = 0; ks < 12; ks++) {
    half8 a0 = *(const half8*)&Af[(((size_t)(m16a * 12 + ks)) << 9) + lane * 8];
    half8 a1 = *(const half8*)&Af[(((size_t)((m16a + 1) * 12 + ks)) << 9) + lane * 8];
    half8 b0 = *(const half8*)&Bf[(((size_t)(nt * 12 + ks) * 4 + wcol * 2 + 0) << 9) + lane * 8];
    half8 b1 = *(const half8*)&Bf[(((size_t)(nt * 12 + ks) * 4 + wcol * 2 + 1) << 9) + lane * 8];
    acc[0][0] = __builtin_amdgcn_mfma_f32_16x16x32_f16(a0, b0, acc[0][0], 0, 0, 0);
    acc[0][1] = __builtin_amdgcn_mfma_f32_16x16x32_f16(a0, b1, acc[0][1], 0, 0, 0);
    acc[1][0] = __builtin_amdgcn_mfma_f32_16x16x32_f16(a1, b0, acc[1][0], 0, 0, 0);
    acc[1][1] = __builtin_amdgcn_mfma_f32_16x16x32_f16(a1, b1, acc[1][1], 0, 0, 0);
  }
  if (nt < 6) {
#pragma unroll
    for (int mi = 0; mi < 2; mi++)
#pragma unroll
      for (int ni = 0; ni < 2; ni++)
#pragma unroll
        for (int r = 0; r < 4; r++)
          Cs[wm + mi * 16 + kg * 4 + r][wcol * 32 + ni * 16 + r16] = acc[mi][ni][r];
    __syncthreads();
    int srow = tid >> 2, fq = tid & 3;
    size_t m = m0 + srow;
    int gc0 = nt * 64 + fq * 16;
#pragma unroll
    for (int c = 0; c < 4; c++) {
      float4 v = *(float4*)&Cs[srow][fq * 16 + c * 4];
      float4 bsv = *(const float4*)&dt_bias[gc0 + c * 4];
      float4 o;
      o.x = softplus_f(v.x + bsv.x);
      o.y = softplus_f(v.y + bsv.y);
      o.z = softplus_f(v.z + bsv.z);
      o.w = softplus_f(v.w + bsv.w);
      *(float4*)&delta[m * DIN + gc0 + c * 4] = o;
    }
  } else {
#pragma unroll
    for (int mi = 0; mi < 2; mi++)
#pragma unroll
      for (int ni = 0; ni < 2; ni++)
#pragma unroll
        for (int r = 0; r < 4; r++) {
          size_t m = m0 + wm + mi * 16 + kg * 4 + r;
          int gc = 384 + wcol * 32 + ni * 16 + r16;
          float val = acc[mi][ni][r];
          if (gc < 400)
            Bmb[m * 16 + (gc - 384)] = val;
          else if (gc < 416)
            Cmb[m * 16 + (gc - 400)] = val;
        }
  }
}

// ---------------------------------------------------------------------------
// Final GEMM: y2h @ W2 (composed out_proj∘proj_out). Transposed per-batch
// store to out [B, C, 4096] via LDS, float4.
// ---------------------------------------------------------------------------
__global__ __launch_bounds__(256) void gemm_final_direct(
    const _Float16* __restrict__ Af, const _Float16* __restrict__ Bf,
    float* __restrict__ C) {
  int mt = blockIdx.x & 255, nt = blockIdx.x >> 8;   // nt 0..2
  int m0 = mt * 64, n0 = nt * 64;
  int tid = threadIdx.x;
  int w = tid >> 6, lane = tid & 63;
  int wm = (w >> 1) * 32, wcol = w & 1;
  int r16 = lane & 15, kg = lane >> 4;
  int m16a = (m0 + wm) >> 4;
  f32x4 acc[2][2] = {};
#pragma unroll
  for (int ks = 0; ks < 12; ks++) {
    half8 a0 = *(const half8*)&Af[(((size_t)(m16a * 12 + ks)) << 9) + lane * 8];
    half8 a1 = *(const half8*)&Af[(((size_t)((m16a + 1) * 12 + ks)) << 9) + lane * 8];
    half8 b0 = *(const half8*)&Bf[(((size_t)(nt * 12 + ks) * 4 + wcol * 2 + 0) << 9) + lane * 8];
    half8 b1 = *(const half8*)&Bf[(((size_t)(nt * 12 + ks) * 4 + wcol * 2 + 1) << 9) + lane * 8];
    acc[0][0] = __builtin_amdgcn_mfma_f32_16x16x32_f16(a0, b0, acc[0][0], 0, 0, 0);
    acc[0][1] = __builtin_amdgcn_mfma_f32_16x16x32_f16(a0, b1, acc[0][1], 0, 0, 0);
    acc[1][0] = __builtin_amdgcn_mfma_f32_16x16x32_f16(a1, b0, acc[1][0], 0, 0, 0);
    acc[1][1] = __builtin_amdgcn_mfma_f32_16x16x32_f16(a1, b1, acc[1][1], 0, 0, 0);
  }
  __shared__ float Cs[64][68];
#pragma unroll
  for (int mi = 0; mi < 2; mi++)
#pragma unroll
    for (int ni = 0; ni < 2; ni++)
#pragma unroll
      for (int r = 0; r < 4; r++)
        Cs[wcol * 32 + ni * 16 + r16][wm + mi * 16 + kg * 4 + r] = acc[mi][ni][r];
  __syncthreads();
  int b = m0 >> 12, l0 = m0 & 4095;
  int o = tid >> 2, fq = tid & 3;
  float* dst = &C[(size_t)(b * CC + n0 + o) * CL + l0 + fq * 16];
#pragma unroll
  for (int c = 0; c < 4; c++)
    *(float4*)&dst[c * 4] = *(float4*)&Cs[o][fq * 16 + c * 4];
}

// ---------------------------------------------------------------------------
// Causal depthwise conv1d (kernel 4) + SiLU, LDS-tiled. Writes fp32 uc and
// fp16 uc_h (A-frag layout).
// ---------------------------------------------------------------------------
__global__ __launch_bounds__(256) void conv_silu_tiled(
    const float* __restrict__ u, const float* __restrict__ cw,
    const float* __restrict__ cb, float* __restrict__ uc,
    _Float16* __restrict__ uc_h) {
  int bid = blockIdx.x;               // b*64*6
  int dg = bid % 6;
  int lt = (bid / 6) % 64;
  int b  = bid / (6 * 64);
  int d0 = dg * 64;
  int l0 = lt * 64;
  __shared__ float S[67][68];
  int t = threadIdx.x;
  for (int idx = t; idx < 67 * 16; idx += 256) {
    int row = idx >> 4, c4i = idx & 15;
    int l = l0 + row - 3;
    float4 v = make_float4(0.f, 0.f, 0.f, 0.f);
    if (l >= 0)
      v = *(const float4*)&u[((size_t)((b << 12) + l)) * DIN + d0 + c4i * 4];
    *(float4*)&S[row][c4i * 4] = v;
  }
  __syncthreads();
  int c4 = t & 15, j0 = (t >> 4) << 2;
  int dd = d0 + c4 * 4;
  float4 cwv[4];
#pragma unroll
  for (int i = 0; i < 4; i++) cwv[i] = *(const float4*)&cw[(dd + i) * 4];
  float4 bias = *(const float4*)&cb[dd];
  float4 win[7];
#pragma unroll
  for (int k = 0; k < 7; k++) win[k] = *(float4*)&S[j0 + k][c4 * 4];
#pragma unroll
  for (int j = 0; j < 4; j++) {
    float4 acc = bias;
#pragma unroll
    for (int k = 0; k < 4; k++) {
      float4 v = win[j + k];
      acc.x = fmaf(v.x, ((const float*)&cwv[0])[k], acc.x);
      acc.y = fmaf(v.y, ((const float*)&cwv[1])[k], acc.y);
      acc.z = fmaf(v.z, ((const float*)&cwv[2])[k], acc.z);
      acc.w = fmaf(v.w, ((const float*)&cwv[3])[k], acc.w);
    }
    acc.x = silu_f(acc.x);
    acc.y = silu_f(acc.y);
    acc.z = silu_f(acc.z);
    acc.w = silu_f(acc.w);
    int l = l0 + j0 + j;
    int m = (b << 12) + l;
    *(float4*)&uc[(size_t)m * DIN + dd] = acc;
    half4 h;
    h[0] = (_Float16)acc.x; h[1] = (_Float16)acc.y;
    h[2] = (_Float16)acc.z; h[3] = (_Float16)acc.w;
    *(half4*)&uc_h[afrag_idx(m, dd, 12)] = h;
  }
}

// ---------------------------------------------------------------------------
// Chunked selective scan, 4 n-states per thread.
// ---------------------------------------------------------------------------
__global__ __launch_bounds__(256) void scan_partial(
    const float* __restrict__ delta, const float* __restrict__ uc,
    const float* __restrict__ Bmb, const float* __restrict__ A_log,
    float* __restrict__ hend, float* __restrict__ Pbuf) {
  int bid = blockIdx.x;
  int chunk = bid & 63, bg = bid >> 6;
  int b = bg / 6, g = bg % 6;
  int t = threadIdx.x;
  int dloc = t >> 2, q = t & 3;
  int d = g * 64 + dloc;
  __shared__ float sD[64][64], sU[64][64], sB[64][16];
  size_t baseBL = ((size_t)b << 12) + chunk * 64;
  {
    int row = t >> 2, cg = (t & 3) * 16;
    const float* dp = &delta[(baseBL + row) * DIN + g * 64 + cg];
    const float* up = &uc[(baseBL + row) * DIN + g * 64 + cg];
#pragma unroll
    for (int c = 0; c < 4; c++) {
      *(float4*)&sD[row][cg + 4 * c] = *(const float4*)&dp[4 * c];
      *(float4*)&sU[row][cg + 4 * c] = *(const float4*)&up[4 * c];
    }
    *(float4*)&sB[row][q * 4] = *(const float4*)&Bmb[(baseBL + row) * 16 + q * 4];
  }
  __syncthreads();
  float4 av = *(const float4*)&A_log[d * 16 + 4 * q];
  float a0 = -__expf(av.x), a1 = -__expf(av.y), a2 = -__expf(av.z), a3 = -__expf(av.w);
  float h0 = 0.f, h1 = 0.f, h2 = 0.f, h3 = 0.f, sdel = 0.f;
#pragma unroll 8
  for (int ll = 0; ll < 64; ll++) {
    float dv = sD[ll][dloc];
    float uv = sU[ll][dloc];
    float4 Bv = *(const float4*)&sB[ll][q * 4];
    float duv = dv * uv;
    h0 = fmaf(__expf(dv * a0), h0, duv * Bv.x);
    h1 = fmaf(__expf(dv * a1), h1, duv * Bv.y);
    h2 = fmaf(__expf(dv * a2), h2, duv * Bv.z);
    h3 = fmaf(__expf(dv * a3), h3, duv * Bv.w);
    sdel += dv;
  }
  size_t e = ((size_t)(b * DIN + d)) * 16 + 4 * q;
  float4 hv; hv.x = h0; hv.y = h1; hv.z = h2; hv.w = h3;
  *(float4*)&hend[(size_t)chunk * NELEM + e] = hv;
  float4 pv;
  pv.x = __expf(a0 * sdel); pv.y = __expf(a1 * sdel);
  pv.z = __expf(a2 * sdel); pv.w = __expf(a3 * sdel);
  *(float4*)&Pbuf[(size_t)chunk * NELEM + e] = pv;
}

__global__ __launch_bounds__(256) void scan_combine(
    const float* __restrict__ hend, const float* __restrict__ Pbuf,
    float* __restrict__ hin) {
  int e = blockIdx.x * 256 + threadIdx.x;   // 0..24575
  float h = 0.f;
  float Pc = Pbuf[e], Hc = hend[e];
#pragma unroll 8
  for (int c = 0; c < NCHUNK; c++) {
    float Pn = 0.f, Hn = 0.f;
    if (c < NCHUNK - 1) {
      Pn = Pbuf[(size_t)(c + 1) * NELEM + e];
      Hn = hend[(size_t)(c + 1) * NELEM + e];
    }
    hin[(size_t)c * NELEM + e] = h;
    h = fmaf(Pc, h, Hc);
    Pc = Pn; Hc = Hn;
  }
}

__global__ __launch_bounds__(256) void scan_final(
    const float* __restrict__ delta, const float* __restrict__ uc,
    const float* __restrict__ Bmb, const float* __restrict__ Cmb,
    const float* __restrict__ A_log, const float* __restrict__ Dskip,
    const float* __restrict__ z, const float* __restrict__ hin,
    float* __restrict__ yr) {
  int bid = blockIdx.x;
  int chunk = bid & 63, bg = bid >> 6;
  int b = bg / 6, g = bg % 6;
  int t = threadIdx.x;
  int dloc = t >> 2, q = t & 3;
  int d = g * 64 + dloc;
  __shared__ float sD[64][64], sU[64][64], sB[64][16], sC[64][16];
  size_t baseBL = ((size_t)b << 12) + chunk * 64;
  {
    int row = t >> 2, cg = (t & 3) * 16;
    const float* dp = &delta[(baseBL + row) * DIN + g * 64 + cg];
    const float* up = &uc[(baseBL + row) * DIN + g * 64 + cg];
#pragma unroll
    for (int c = 0; c < 4; c++) {
      *(float4*)&sD[row][cg + 4 * c] = *(const float4*)&dp[4 * c];
      *(float4*)&sU[row][cg + 4 * c] = *(const float4*)&up[4 * c];
    }
    *(float4*)&sB[row][q * 4] = *(const float4*)&Bmb[(baseBL + row) * 16 + q * 4];
    *(float4*)&sC[row][q * 4] = *(const float4*)&Cmb[(baseBL + row) * 16 + q * 4];
  }
  __syncthreads();
  float4 av = *(const float4*)&A_log[d * 16 + 4 * q];
  float a0 = -__expf(av.x), a1 = -__expf(av.y), a2 = -__expf(av.z), a3 = -__expf(av.w);
  size_t e = ((size_t)(b * DIN + d)) * 16 + 4 * q;
  float4 hv = *(const float4*)&hin[(size_t)chunk * NELEM + e];
  float h0 = hv.x, h1 = hv.y, h2 = hv.z, h3 = hv.w;
  float yk[16];
#pragma unroll
  for (int ll = 0; ll < 64; ll++) {
    float dv = sD[ll][dloc];
    float uv = sU[ll][dloc];
    float4 Bv = *(const float4*)&sB[ll][q * 4];
    float4 Cv = *(const float4*)&sC[ll][q * 4];
    float duv = dv * uv;
    h0 = fmaf(__expf(dv * a0), h0, duv * Bv.x);
    h1 = fmaf(__expf(dv * a1), h1, duv * Bv.y);
    h2 = fmaf(__expf(dv * a2), h2, duv * Bv.z);
    h3 = fmaf(__expf(dv * a3), h3, duv * Bv.w);
    float yp = h0 * Cv.x + h1 * Cv.y + h2 * Cv.z + h3 * Cv.w;
    yp += quadswz<0x041F>(yp);   // xor 1 within quad
    yp += quadswz<0x081F>(yp);   // xor 2 within quad -> all 4 lanes have sum
    if ((ll & 3) == q) yk[ll >> 2] = yp;
  }
  float dsk = Dskip[d];
  bool odd = chunk & 1;
  // Un-snake into sD (dead) with the Dskip term; only own column touched.
#pragma unroll
  for (int i = 0; i < 16; i++) {
    int ll = 4 * i + q;
    int wr = odd ? 63 - ll : ll;
    sD[wr][dloc] = yk[i] + sU[ll][dloc] * dsk;
  }
  __syncthreads();
  // Vectorized gate + store: float4 z read, float4 yr write.
  int srow = t >> 2, fq = t & 3;
  size_t ro = baseBL + srow;
#pragma unroll
  for (int c = 0; c < 4; c++) {
    float4 yv = *(float4*)&sD[srow][fq * 16 + c * 4];
    float4 zv = *(const float4*)&z[ro * DIN + g * 64 + fq * 16 + c * 4];
    float4 o;
    o.x = yv.x * silu_f(zv.x);
    o.y = yv.y * silu_f(zv.y);
    o.z = yv.z * silu_f(zv.z);
    o.w = yv.w * silu_f(zv.w);
    *(float4*)&yr[ro * DIN + g * 64 + fq * 16 + c * 4] = o;
  }
}

// ---------------------------------------------------------------------------
// Depthwise 3x3 local enhancement + residual, LDS-tiled -> fp16 A-frags.
// ---------------------------------------------------------------------------
__global__ __launch_bounds__(256) void le_conv_tiled(
    const float* __restrict__ yr, const float* __restrict__ lwT,
    _Float16* __restrict__ y2h) {
  int bid = blockIdx.x;               // ((b*16 + ht)*24 + dg)
  int dg = bid % 24;
  int ht = (bid / 24) % 16;
  int b  = bid / (24 * 16);
  int d0 = dg * 16;
  int h0 = ht * 4;
  __shared__ float S[6][66][24];
  int t = threadIdx.x;
  int dq = t & 3, w = t >> 2;
#pragma unroll
  for (int r = 0; r < 6; r++) {
    int hh = h0 - 1 + r;
    float4 v = make_float4(0.f, 0.f, 0.f, 0.f);
    if (hh >= 0 && hh < 64)
      v = *(const float4*)&yr[((size_t)((b << 12) + (hh << 6) + w)) * DIN + d0 + dq * 4];
    *(float4*)&S[r][w + 1][dq * 4] = v;
    if (w == 0)  *(float4*)&S[r][0][dq * 4]  = make_float4(0.f, 0.f, 0.f, 0.f);
    if (w == 63) *(float4*)&S[r][65][dq * 4] = make_float4(0.f, 0.f, 0.f, 0.f);
  }
  __syncthreads();
  float4 wv[9];
#pragma unroll
  for (int i = 0; i < 9; i++)
    wv[i] = *(const float4*)&lwT[i * DIN + d0 + dq * 4];
#pragma unroll
  for (int hr = 0; hr < 4; hr++) {
    float4 acc = *(float4*)&S[hr + 1][w + 1][dq * 4];   // residual
#pragma unroll
    for (int ki = 0; ki < 3; ki++)
#pragma unroll
      for (int kj = 0; kj < 3; kj++) {
        float4 v = *(float4*)&S[hr + ki][w + kj][dq * 4];
        float4 c = wv[ki * 3 + kj];
        acc.x = fmaf(v.x, c.x, acc.x);
        acc.y = fmaf(v.y, c.y, acc.y);
        acc.z = fmaf(v.z, c.z, acc.z);
        acc.w = fmaf(v.w, c.w, acc.w);
      }
    int l = ((h0 + hr) << 6) + w;
    int m = (b << 12) + l;
    half4 h;
    h[0] = (_Float16)acc.x; h[1] = (_Float16)acc.y;
    h[2] = (_Float16)acc.z; h[3] = (_Float16)acc.w;
    *(half4*)&y2h[afrag_idx(m, d0 + dq * 4, 12)] = h;
  }
}

// ---------------------------------------------------------------------------
extern "C" void kernel_launch(void* const* d_in, const int* in_sizes, int n_in,
                              void* d_out, int out_size, void* d_ws, size_t ws_size,
                              hipStream_t stream) {
  const float* x          = (const float*)d_in[0];
  const float* gn_gamma   = (const float*)d_in[1];
  const float* gn_beta    = (const float*)d_in[2];
  const float* in_proj_w  = (const float*)d_in[3];
  const float* conv1d_w   = (const float*)d_in[4];
  const float* conv1d_b   = (const float*)d_in[5];
  const float* x_proj_w   = (const float*)d_in[6];
  const float* dt_proj_w  = (const float*)d_in[7];
  const float* dt_proj_b  = (const float*)d_in[8];
  const float* A_log      = (const float*)d_in[9];
  const float* Dskip      = (const float*)d_in[10];
  const float* le_w       = (const float*)d_in[11];
  const float* out_proj_w = (const float*)d_in[12];
  const float* proj_out_w = (const float*)d_in[13];
  float* out = (float*)d_out;

  float* ws      = (float*)d_ws;
  float* part    = ws + WS_PART;
  float* stat    = ws + WS_STAT;
  _Float16* BfIn = (_Float16*)(ws + WS_BFIN);
  _Float16* W2f  = (_Float16*)(ws + WS_W2F);
  _Float16* BfXf = (_Float16*)(ws + WS_BFXF);
  float* lwT    = ws + WS_LWT;
  float* u      = ws + WS_BIG;
  float* zb     = u + BIGSZ;
  float* uc     = zb + BIGSZ;
  float* delta  = uc + BIGSZ;
  float* yr     = delta + BIGSZ;
  float* Bmb    = yr + BIGSZ;
  float* Cmb    = Bmb + NBL * NST;
  // fp16 frag buffers aliased into temporally-dead fp32 regions:
  _Float16* uc_h = (_Float16*)yr;     // live conv_silu -> xfull (yr written later)
  _Float16* y2h  = (_Float16*)delta;  // live le_conv -> final gemm (delta dead)
  // scan scratch aliases u (dead after conv_silu)
  float* hend   = u;
  float* Pbuf   = u + (size_t)NCHUNK * NELEM;
  float* hin    = u + 2 * (size_t)NCHUNK * NELEM;

  prep_kernel<<<1536, 256, 0, stream>>>(x, in_proj_w, x_proj_w, dt_proj_w,
                                        out_proj_w, proj_out_w, le_w, ws);
  gn_final<<<1, 256, 0, stream>>>(part, stat);
  gemm_inproj_mfma<<<256 * 12, 256, 0, stream>>>(x, BfIn, stat, gn_gamma, gn_beta, u, zb);
  conv_silu_tiled<<<1536, 256, 0, stream>>>(u, conv1d_w, conv1d_b, uc, uc_h);
  xfull_direct<<<256 * 7, 256, 0, stream>>>(uc_h, BfXf, dt_proj_b, delta, Bmb, Cmb);
  scan_partial<<<1536, 256, 0, stream>>>(delta, uc, Bmb, A_log, hend, Pbuf);
  scan_combine<<<96, 256, 0, stream>>>(hend, Pbuf, hin);
  scan_final<<<1536, 256, 0, stream>>>(delta, uc, Bmb, Cmb, A_log, Dskip,
                                       zb, hin, yr);
  le_conv_tiled<<<1536, 256, 0, stream>>>(yr, lwT, y2h);
  gemm_final_direct<<<256 * 3, 256, 0, stream>>>(y2h, W2f, out);
}